// Round 7
// baseline (2616.856 us; speedup 1.0000x reference)
//
#include <hip/hip_runtime.h>
#include <stdint.h>

#define NN 100000
#define EE 1600000
#define NLAYERS 5
#define BN_EPS 1e-5f
#define NCHUNK 98    // ceil(NN/1024)
#define RR 4         // node ranges (25K nodes each -> 100KB LDS hist)
#define SS 64        // edge slices
#define NPR 25000    // nodes per range
#define ESL 25000    // edges per slice

typedef __attribute__((ext_vector_type(8))) short short8;
typedef __attribute__((ext_vector_type(4))) float f32x4;

union S8 { short8 v; uint32_t u[4]; };

__device__ inline uint16_t bf16r(float a){
  uint32_t u = __float_as_uint(a);
  u = (u + 0x7fffu + ((u >> 16) & 1u)) >> 16;
  return (uint16_t)u;
}
__device__ inline uint32_t pack2(float a, float b){
  return (uint32_t)bf16r(a) | ((uint32_t)bf16r(b) << 16);
}
__device__ inline float bflo(uint32_t v){ return __uint_as_float(v << 16); }
__device__ inline float bfhi(uint32_t v){ return __uint_as_float(v & 0xffff0000u); }

// ---------------- edge dtype detection (int64 vs int32, JAX x64 ambiguity) ----
__global__ void k_detect(const long long* e, int* flag){
  if (threadIdx.x == 0){
    int f = 1;
    for (int i = 0; i < 8; i++){ long long v = e[i]; if (v < 0 || v >= NN) f = 0; }
    *flag = f;  // 1 => int64 data, 0 => int32 data
  }
}

// ---------------- edge convert to int32 (src at [0,E), dst at [E,2E)) ---------
__global__ __launch_bounds__(256) void k_conv(const void* ep, const int* __restrict__ flag,
                                              int* __restrict__ e32o){
  int f = *flag;
  int i = blockIdx.x * 256 + threadIdx.x, stride = gridDim.x * 256;
  const long long* e64 = (const long long*)ep;
  const int* ei = (const int*)ep;
  for (; i < 2 * EE; i += stride) e32o[i] = f ? (int)e64[i] : ei[i];
}

// ---------------- pass A: per-(slice,range) LDS histogram, no global atomics --
__global__ __launch_bounds__(512) void k_hist(const int* __restrict__ dst, int* __restrict__ bh){
  __shared__ int hist[NPR];  // 100KB
  int b = blockIdx.x;
  int r = (b & 7) >> 1;
  int s = ((b >> 3) << 1) | (b & 1);
  int lo = r * NPR;
  for (int i = threadIdx.x; i < NPR; i += 512) hist[i] = 0;
  __syncthreads();
  int beg = s * ESL;
  for (int i = beg + threadIdx.x; i < beg + ESL; i += 512){
    int d = dst[i] - lo;
    if ((unsigned)d < NPR) atomicAdd(&hist[d], 1);
  }
  __syncthreads();
  for (int i = threadIdx.x; i < NPR; i += 512)
    bh[(size_t)s * NN + lo + i] = hist[i];
}

// ---------------- cross-slice exclusive scan per node; total -> deg -----------
__global__ __launch_bounds__(256) void k_scanhist(int* __restrict__ bh, int* __restrict__ deg){
  int n = blockIdx.x * 256 + threadIdx.x;
  if (n < NN){
    int run = 0;
    #pragma unroll 4
    for (int s = 0; s < SS; s++){
      size_t p = (size_t)s * NN + n;
      int v = bh[p]; bh[p] = run; run += v;
    }
    deg[n] = run;
  }
}

// ---------------- global node scan (3 kernels) ----------------
__global__ void k_chunksum(const int* __restrict__ deg, int* __restrict__ csum){
  __shared__ int sh[256];
  int chunk = blockIdx.x, t = threadIdx.x;
  int base = chunk * 1024 + t * 4;
  int s = 0;
  #pragma unroll
  for (int j = 0; j < 4; j++){ int idx = base + j; if (idx < NN) s += deg[idx]; }
  sh[t] = s; __syncthreads();
  for (int off = 128; off > 0; off >>= 1){
    if (t < off) sh[t] += sh[t + off];
    __syncthreads();
  }
  if (t == 0) csum[chunk] = sh[0];
}

__global__ void k_scancsum(int* csum, int* rowStart){
  __shared__ int sh[128];
  int t = threadIdx.x;
  int v = (t < NCHUNK) ? csum[t] : 0;
  sh[t] = v; __syncthreads();
  for (int off = 1; off < 128; off <<= 1){
    int x = (t >= off) ? sh[t - off] : 0;
    __syncthreads();
    sh[t] += x;
    __syncthreads();
  }
  if (t < NCHUNK) csum[t] = sh[t] - v;  // exclusive
  if (t == 0) rowStart[NN] = EE;
}

__global__ void k_scanwithin(const int* __restrict__ deg, const int* __restrict__ csum,
                             int* __restrict__ rowStart){
  __shared__ int sh[256];
  int chunk = blockIdx.x, t = threadIdx.x;
  int base = chunk * 1024 + t * 4;
  int v[4];
  #pragma unroll
  for (int j = 0; j < 4; j++){ int idx = base + j; v[j] = (idx < NN) ? deg[idx] : 0; }
  int tot = v[0] + v[1] + v[2] + v[3];
  sh[t] = tot; __syncthreads();
  for (int off = 1; off < 256; off <<= 1){
    int x = (t >= off) ? sh[t - off] : 0;
    __syncthreads();
    sh[t] += x;
    __syncthreads();
  }
  int run = csum[chunk] + sh[t] - tot;
  #pragma unroll
  for (int j = 0; j < 4; j++){
    int idx = base + j;
    if (idx < NN){ rowStart[idx] = run; run += v[j]; }
  }
}

// ---------------- pass B: scatter with LDS cursor (no global atomics) ---------
__global__ __launch_bounds__(512) void k_scatter(const int* __restrict__ src,
    const int* __restrict__ dst, const int* __restrict__ rowStart,
    const int* __restrict__ bh, int* __restrict__ adj){
  __shared__ int cur[NPR];  // 100KB
  int b = blockIdx.x;
  int r = (b & 7) >> 1;
  int s = ((b >> 3) << 1) | (b & 1);
  int lo = r * NPR;
  for (int i = threadIdx.x; i < NPR; i += 512)
    cur[i] = rowStart[lo + i] + bh[(size_t)s * NN + lo + i];
  __syncthreads();
  int beg = s * ESL;
  for (int i = beg + threadIdx.x; i < beg + ESL; i += 512){
    int d = dst[i] - lo;
    if ((unsigned)d < NPR){
      int pos = atomicAdd(&cur[d], 1);
      adj[pos] = src[i];
    }
  }
}

__global__ void k_invdeg(const int* __restrict__ deg, float* __restrict__ invd){
  int i = blockIdx.x * blockDim.x + threadIdx.x;
  if (i < NN) invd[i] = 1.0f / fmaxf((float)deg[i], 1.0f);
}

// ---------------- casts ----------------
__global__ void k_castx(const float* __restrict__ x, uint32_t* __restrict__ B0){
  int i = blockIdx.x * 256 + threadIdx.x, stride = gridDim.x * 256;
  for (; i < NN * 64; i += stride){
    int row = i >> 6, c = (i & 63) << 1;
    B0[i] = pack2(x[row * 128 + c], x[row * 128 + c + 1]);
  }
}

// weights pre-arranged to LDS-friendly [k/4][col][4] bf16 layout
__global__ void k_castw(const float* __restrict__ Wl_g, const float* __restrict__ Wr_g,
                        const float* __restrict__ Wo_g, uint16_t* __restrict__ wbf,
                        uint16_t* __restrict__ wobf){
  int i = blockIdx.x * 256 + threadIdx.x, stride = gridDim.x * 256;
  for (; i < 172032; i += stride){
    if (i < 163840){
      int l = i >> 15, r = i & 32767;
      int kc = r >> 9, rem = r & 511, col = rem >> 2, k3 = rem & 3;
      int k = kc * 4 + k3;
      float v = (k < 128) ? Wl_g[l * 16384 + k * 128 + col]
                          : Wr_g[l * 16384 + (k - 128) * 128 + col];
      wbf[i] = bf16r(v);
    } else {
      int j = i - 163840;
      int kc = j >> 8, rem = j & 255, col = rem >> 2, k3 = rem & 3;
      int k = kc * 4 + k3;
      wobf[j] = bf16r(Wo_g[k * 64 + col]);
    }
  }
}

// ---------------- aggregation v3: column-sliced, XCD-L2-local gather ----------
// block b: column-group cg=b&7 (32B slice; intended to pin to one XCD whose L2
// then only sees a 3.2MB h-slice -> resident), node sub-block sb=b>>3.
// Wave handles 16 edges per iter: sub=lane>>3 picks edge, lc=lane&7 picks uint32.
__global__ __launch_bounds__(256) void k_agg(const uint32_t* __restrict__ h,
    const int* __restrict__ rs, const int* __restrict__ adj,
    const float* __restrict__ invd, uint32_t* __restrict__ agg){
  int b = blockIdx.x;
  int cg = b & 7;
  int sb = b >> 3;
  int t = threadIdx.x;
  int w = t >> 6, lane = t & 63;
  int sub = lane >> 3;
  int lc = lane & 7;
  const uint32_t* hc = h + cg * 8 + lc;
  int nbeg = sb * 391;
  int nend = min(nbeg + 391, NN);
  for (int node = nbeg + w; node < nend; node += 4){
    int s = __builtin_nontemporal_load(rs + node);
    int e = __builtin_nontemporal_load(rs + node + 1);
    int len = e - s;
    float a0 = 0.f, a1 = 0.f;
    if (len > 0){
      int nch = (len + 15) >> 4;
      for (int c = 0; c < nch; c++){
        int base = s + c * 16 + sub;
        int p0 = min(base, e - 1);
        int p1 = min(base + 8, e - 1);
        int r0 = __builtin_nontemporal_load(adj + p0);
        int r1 = __builtin_nontemporal_load(adj + p1);
        uint32_t v0 = hc[r0 * 64];
        uint32_t v1 = hc[r1 * 64];
        a0 += bflo(v0) + bflo(v1);
        a1 += bfhi(v0) + bfhi(v1);
      }
      // reduce over the 8 edge-subgroups (lane stride 8)
      a0 += __shfl_xor(a0, 8);  a1 += __shfl_xor(a1, 8);
      a0 += __shfl_xor(a0, 16); a1 += __shfl_xor(a1, 16);
      a0 += __shfl_xor(a0, 32); a1 += __shfl_xor(a1, 32);
      int pad = nch * 16 - len;
      if (pad){
        int rl = __builtin_nontemporal_load(adj + e - 1);
        uint32_t vl = hc[rl * 64];
        float fp = (float)pad;
        a0 -= fp * bflo(vl);
        a1 -= fp * bfhi(vl);
      }
    }
    if (sub == 0){
      float id = invd[node];
      uint32_t o = pack2(a0 * id, a1 * id);
      __builtin_nontemporal_store(o, agg + node * 64 + cg * 8 + lc);
    }
  }
}

// ---------------- fused GEMM: raw = [agg|h] @ [W_l;W_r] + b, + BN stats ------
// 512 threads = 8 waves x 32 rows: 2x occupancy vs 4-wave version (A-gather
// latency was the bottleneck at ~6 waves/CU).
__global__ __launch_bounds__(512) void k_gemm(const uint16_t* __restrict__ A0,
    const uint16_t* __restrict__ A1, const uint16_t* __restrict__ Wg,
    const float* __restrict__ bias, uint16_t* __restrict__ raw, float* __restrict__ stats){
  __shared__ uint16_t Wl[32768];  // 64KB: [k/4][128][4]
  int t = threadIdx.x;
  {
    const uint4* gw = (const uint4*)Wg;
    uint4* lw = (uint4*)Wl;
    #pragma unroll
    for (int i = 0; i < 8; i++) lw[t + i * 512] = gw[t + i * 512];
  }
  __syncthreads();
  int lane = t & 63, wid = t >> 6;     // 8 waves
  int rbase = blockIdx.x * 256 + wid * 32;
  int lm = lane & 15, lq = lane >> 4;
  const uint16_t* pa[2]; const uint16_t* ph[2];
  #pragma unroll
  for (int rf = 0; rf < 2; rf++){
    int grow = rbase + rf * 16 + lm;
    int crow = grow < NN ? grow : NN - 1;
    pa[rf] = A0 + (size_t)crow * 128;
    ph[rf] = A1 + (size_t)crow * 128;
  }
  int koffA = lq * 4;
  const uint16_t* wb = Wl + lq * 512 + lm * 4;
  f32x4 acc[2][8];
  #pragma unroll
  for (int rf = 0; rf < 2; rf++)
    #pragma unroll
    for (int c = 0; c < 8; c++){ acc[rf][c][0]=0.f; acc[rf][c][1]=0.f; acc[rf][c][2]=0.f; acc[rf][c][3]=0.f; }

  #pragma unroll
  for (int ch = 0; ch < 8; ++ch){
    const int kc = (ch & 3) * 32;
    S8 a[2];
    #pragma unroll
    for (int rf = 0; rf < 2; rf++){
      const uint16_t* p = (ch < 4 ? pa[rf] : ph[rf]) + kc + koffA;
      uint2 t0 = *(const uint2*)p;
      uint2 t1 = *(const uint2*)(p + 16);
      a[rf].u[0] = t0.x; a[rf].u[1] = t0.y; a[rf].u[2] = t1.x; a[rf].u[3] = t1.y;
    }
    const uint16_t* wc = wb + ch * 4096;
    #pragma unroll
    for (int cc = 0; cc < 8; cc++){
      S8 b;
      uint2 t0 = *(const uint2*)(wc + cc * 64);
      uint2 t1 = *(const uint2*)(wc + cc * 64 + 2048);
      b.u[0] = t0.x; b.u[1] = t0.y; b.u[2] = t1.x; b.u[3] = t1.y;
      #pragma unroll
      for (int rf = 0; rf < 2; rf++)
        acc[rf][cc] = __builtin_amdgcn_mfma_f32_16x16x32_bf16(a[rf].v, b.v, acc[rf][cc], 0, 0, 0);
    }
  }

  float bs[8];
  #pragma unroll
  for (int cc = 0; cc < 8; cc++) bs[cc] = bias[cc * 16 + lm];
  float sm[8] = {0,0,0,0,0,0,0,0}, sq[8] = {0,0,0,0,0,0,0,0};
  #pragma unroll
  for (int rf = 0; rf < 2; rf++){
    int rowb = rbase + rf * 16 + lq * 4;
    #pragma unroll
    for (int r = 0; r < 4; r++){
      int grow = rowb + r;
      if (grow < NN){
        uint16_t* orow = raw + (size_t)grow * 128 + lm;
        #pragma unroll
        for (int cc = 0; cc < 8; cc++){
          float v = acc[rf][cc][r] + bs[cc];
          orow[cc * 16] = bf16r(v);
          sm[cc] += v; sq[cc] += v * v;
        }
      }
    }
  }
  #pragma unroll
  for (int cc = 0; cc < 8; cc++){
    sm[cc] += __shfl_xor(sm[cc], 16); sm[cc] += __shfl_xor(sm[cc], 32);
    sq[cc] += __shfl_xor(sq[cc], 16); sq[cc] += __shfl_xor(sq[cc], 32);
  }
  if (lq == 0){
    #pragma unroll
    for (int cc = 0; cc < 8; cc++){
      atomicAdd(&stats[cc * 16 + lm], sm[cc]);
      atomicAdd(&stats[128 + cc * 16 + lm], sq[cc]);
    }
  }
}

// ---------------- BN+ReLU apply (computes coef per block from stats) ----------
__global__ __launch_bounds__(256) void k_bnrelu(const uint32_t* __restrict__ raw,
    uint32_t* __restrict__ hn, const float* __restrict__ stats,
    const float* __restrict__ gamma, const float* __restrict__ beta){
  __shared__ float cf[256];
  int t = threadIdx.x;
  if (t < 128){
    float mean = stats[t] * (1.0f / NN);
    float var = fmaxf(stats[128 + t] * (1.0f / NN) - mean * mean, 0.f);
    float a = gamma[t] * rsqrtf(var + BN_EPS);
    cf[t] = a;
    cf[128 + t] = beta[t] - mean * a;
  }
  __syncthreads();
  const uint2* rp = (const uint2*)raw;
  uint2* op = (uint2*)hn;
  int i = blockIdx.x * 256 + t, stride = gridDim.x * 256;
  for (; i < NN * 32; i += stride){
    uint2 v = rp[i];
    int c = (i & 31) * 4;
    float x0 = fmaxf(fmaf(bflo(v.x), cf[c],     cf[128 + c]),     0.f);
    float x1 = fmaxf(fmaf(bfhi(v.x), cf[c + 1], cf[129 + c]),     0.f);
    float x2 = fmaxf(fmaf(bflo(v.y), cf[c + 2], cf[130 + c]),     0.f);
    float x3 = fmaxf(fmaf(bfhi(v.y), cf[c + 3], cf[131 + c]),     0.f);
    uint2 o;
    o.x = pack2(x0, x1);
    o.y = pack2(x2, x3);
    op[i] = o;
  }
}

// ---------------- final projection: out = h @ W_o + b_o (f32 out) ------------
__global__ __launch_bounds__(512) void k_gemmout(const uint16_t* __restrict__ A1,
    const uint16_t* __restrict__ Wg, const float* __restrict__ bo, float* __restrict__ out){
  __shared__ uint16_t Wl[8192];  // 16KB: [k/4][64][4]
  int t = threadIdx.x;
  {
    const uint4* gw = (const uint4*)Wg;
    uint4* lw = (uint4*)Wl;
    #pragma unroll
    for (int i = 0; i < 2; i++) lw[t + i * 512] = gw[t + i * 512];
  }
  __syncthreads();
  int lane = t & 63, wid = t >> 6;
  int rbase = blockIdx.x * 256 + wid * 32;
  int lm = lane & 15, lq = lane >> 4;
  const uint16_t* ph[2];
  #pragma unroll
  for (int rf = 0; rf < 2; rf++){
    int grow = rbase + rf * 16 + lm;
    int crow = grow < NN ? grow : NN - 1;
    ph[rf] = A1 + (size_t)crow * 128;
  }
  const uint16_t* wbp = Wl + lq * 256 + lm * 4;
  f32x4 acc[2][4];
  #pragma unroll
  for (int rf = 0; rf < 2; rf++)
    #pragma unroll
    for (int c = 0; c < 4; c++){ acc[rf][c][0]=0.f; acc[rf][c][1]=0.f; acc[rf][c][2]=0.f; acc[rf][c][3]=0.f; }
  #pragma unroll
  for (int ch = 0; ch < 4; ++ch){
    int kc = ch * 32;
    S8 a[2];
    #pragma unroll
    for (int rf = 0; rf < 2; rf++){
      const uint16_t* p = ph[rf] + kc + lq * 4;
      uint2 t0 = *(const uint2*)p;
      uint2 t1 = *(const uint2*)(p + 16);
      a[rf].u[0] = t0.x; a[rf].u[1] = t0.y; a[rf].u[2] = t1.x; a[rf].u[3] = t1.y;
    }
    const uint16_t* wc = wbp + ch * 2048;
    #pragma unroll
    for (int cc = 0; cc < 4; cc++){
      S8 b;
      uint2 t0 = *(const uint2*)(wc + cc * 64);
      uint2 t1 = *(const uint2*)(wc + cc * 64 + 1024);
      b.u[0] = t0.x; b.u[1] = t0.y; b.u[2] = t1.x; b.u[3] = t1.y;
      #pragma unroll
      for (int rf = 0; rf < 2; rf++)
        acc[rf][cc] = __builtin_amdgcn_mfma_f32_16x16x32_bf16(a[rf].v, b.v, acc[rf][cc], 0, 0, 0);
    }
  }
  float bs[4];
  #pragma unroll
  for (int cc = 0; cc < 4; cc++) bs[cc] = bo[cc * 16 + lm];
  #pragma unroll
  for (int rf = 0; rf < 2; rf++){
    int rowb = rbase + rf * 16 + lq * 4;
    #pragma unroll
    for (int r = 0; r < 4; r++){
      int grow = rowb + r;
      if (grow < NN){
        float* orow = out + (size_t)grow * 64 + lm;
        #pragma unroll
        for (int cc = 0; cc < 4; cc++) orow[cc * 16] = acc[rf][cc][r] + bs[cc];
      }
    }
  }
}

extern "C" void kernel_launch(void* const* d_in, const int* in_sizes, int n_in,
                              void* d_out, int out_size, void* d_ws, size_t ws_size,
                              hipStream_t stream){
  const float* x      = (const float*)d_in[0];
  const void*  edges  = d_in[1];
  const float* Wl_g   = (const float*)d_in[2];
  const float* bl_g   = (const float*)d_in[3];
  const float* Wr_g   = (const float*)d_in[4];
  const float* gm_g   = (const float*)d_in[5];
  const float* bt_g   = (const float*)d_in[6];
  const float* Wo_g   = (const float*)d_in[7];
  const float* bo_g   = (const float*)d_in[8];
  float* out = (float*)d_out;

  char* ws = (char*)d_ws;
  size_t off = 0;
  auto alloc = [&](size_t bytes) -> char* {
    char* p = ws + off;
    off = (off + bytes + 255) & ~(size_t)255;
    return p;
  };
  int*      flag     = (int*)alloc(4);
  int*      deg      = (int*)alloc(4 * NN);
  int*      rowStart = (int*)alloc(4 * (NN + 1));
  float*    invd     = (float*)alloc(4 * NN);
  int*      csum     = (int*)alloc(4 * 128);
  int*      adj      = (int*)alloc(4 * (EE + 8));
  uint16_t* wbf      = (uint16_t*)alloc(2 * 5 * 32768);
  uint16_t* wobf     = (uint16_t*)alloc(2 * 8192);
  float*    stats    = (float*)alloc(4 * 256 * NLAYERS);  // per-layer segments
  const size_t NPAD = 100096;  // 391 * 256
  uint16_t* B0 = (uint16_t*)alloc(2 * NPAD * 128);  // h_norm (state)
  uint16_t* B1 = (uint16_t*)alloc(2 * NPAD * 128);  // raw
  uint16_t* B2 = (uint16_t*)alloc(2 * NPAD * 128);  // agg
  // aliases: both dead before the layer loop's first writes to B1/B2
  int* e32 = (int*)B2;   // 12.8MB  (consumed by k_scatter)
  int* bh  = (int*)B1;   // 25.6MB  (SS*NN*4 = 25.6e6 <= 25.62e6)

  hipMemsetAsync(stats, 0, 4 * 256 * NLAYERS, stream);

  k_detect<<<1, 64, 0, stream>>>((const long long*)edges, flag);
  k_conv<<<2048, 256, 0, stream>>>(edges, flag, e32);
  k_hist<<<RR * SS, 512, 0, stream>>>(e32 + EE, bh);
  k_scanhist<<<391, 256, 0, stream>>>(bh, deg);
  k_chunksum<<<NCHUNK, 256, 0, stream>>>(deg, csum);
  k_scancsum<<<1, 128, 0, stream>>>(csum, rowStart);
  k_scanwithin<<<NCHUNK, 256, 0, stream>>>(deg, csum, rowStart);
  k_invdeg<<<391, 256, 0, stream>>>(deg, invd);
  k_scatter<<<RR * SS, 512, 0, stream>>>(e32, e32 + EE, rowStart, bh, adj);
  k_castx<<<2048, 256, 0, stream>>>(x, (uint32_t*)B0);
  k_castw<<<256, 256, 0, stream>>>(Wl_g, Wr_g, Wo_g, wbf, wobf);

  for (int l = 0; l < NLAYERS; l++){
    float* st = stats + (size_t)l * 256;
    k_agg<<<2048, 256, 0, stream>>>((const uint32_t*)B0, rowStart, adj, invd, (uint32_t*)B2);
    k_gemm<<<391, 512, 0, stream>>>(B2, B0, wbf + (size_t)l * 32768, bl_g + l * 128, B1, st);
    k_bnrelu<<<2048, 256, 0, stream>>>((const uint32_t*)B1, (uint32_t*)B0, st,
                                       gm_g + l * 128, bt_g + l * 128);
  }
  k_gemmout<<<391, 512, 0, stream>>>(B0, wobf, bo_g, out);
}

// Round 8
// 1004.459 us; speedup vs baseline: 2.6052x; 2.6052x over previous
//
#include <hip/hip_runtime.h>
#include <stdint.h>

#define NN 100000
#define EE 1600000
#define NLAYERS 5
#define BN_EPS 1e-5f
#define NCHUNK 98    // ceil(NN/1024)
#define RR 4         // node ranges (25K nodes each -> 100KB LDS hist)
#define SS 64        // edge slices
#define NPR 25000    // nodes per range
#define ESL 25000    // edges per slice

typedef __attribute__((ext_vector_type(8))) short short8;
typedef __attribute__((ext_vector_type(4))) float f32x4;

union S8 { short8 v; uint32_t u[4]; };

__device__ inline uint16_t bf16r(float a){
  uint32_t u = __float_as_uint(a);
  u = (u + 0x7fffu + ((u >> 16) & 1u)) >> 16;
  return (uint16_t)u;
}
__device__ inline uint32_t pack2(float a, float b){
  return (uint32_t)bf16r(a) | ((uint32_t)bf16r(b) << 16);
}
__device__ inline float bflo(uint32_t v){ return __uint_as_float(v << 16); }
__device__ inline float bfhi(uint32_t v){ return __uint_as_float(v & 0xffff0000u); }

// ---------------- edge dtype detection (int64 vs int32, JAX x64 ambiguity) ----
__global__ void k_detect(const long long* e, int* flag){
  if (threadIdx.x == 0){
    int f = 1;
    for (int i = 0; i < 8; i++){ long long v = e[i]; if (v < 0 || v >= NN) f = 0; }
    *flag = f;  // 1 => int64 data, 0 => int32 data
  }
}

// ---------------- edge convert to int32 (src at [0,E), dst at [E,2E)) ---------
__global__ __launch_bounds__(256) void k_conv(const void* ep, const int* __restrict__ flag,
                                              int* __restrict__ e32o){
  int f = *flag;
  int i = blockIdx.x * 256 + threadIdx.x, stride = gridDim.x * 256;
  const long long* e64 = (const long long*)ep;
  const int* ei = (const int*)ep;
  for (; i < 2 * EE; i += stride) e32o[i] = f ? (int)e64[i] : ei[i];
}

// ---------------- pass A: per-(slice,range) LDS histogram, no global atomics --
__global__ __launch_bounds__(512) void k_hist(const int* __restrict__ dst, int* __restrict__ bh){
  __shared__ int hist[NPR];  // 100KB
  int b = blockIdx.x;
  int r = (b & 7) >> 1;
  int s = ((b >> 3) << 1) | (b & 1);
  int lo = r * NPR;
  for (int i = threadIdx.x; i < NPR; i += 512) hist[i] = 0;
  __syncthreads();
  int beg = s * ESL;
  for (int i = beg + threadIdx.x; i < beg + ESL; i += 512){
    int d = dst[i] - lo;
    if ((unsigned)d < NPR) atomicAdd(&hist[d], 1);
  }
  __syncthreads();
  for (int i = threadIdx.x; i < NPR; i += 512)
    bh[(size_t)s * NN + lo + i] = hist[i];
}

// ---------------- cross-slice exclusive scan per node; total -> deg -----------
__global__ __launch_bounds__(256) void k_scanhist(int* __restrict__ bh, int* __restrict__ deg){
  int n = blockIdx.x * 256 + threadIdx.x;
  if (n < NN){
    int run = 0;
    #pragma unroll 4
    for (int s = 0; s < SS; s++){
      size_t p = (size_t)s * NN + n;
      int v = bh[p]; bh[p] = run; run += v;
    }
    deg[n] = run;
  }
}

// ---------------- global node scan (3 kernels) ----------------
__global__ void k_chunksum(const int* __restrict__ deg, int* __restrict__ csum){
  __shared__ int sh[256];
  int chunk = blockIdx.x, t = threadIdx.x;
  int base = chunk * 1024 + t * 4;
  int s = 0;
  #pragma unroll
  for (int j = 0; j < 4; j++){ int idx = base + j; if (idx < NN) s += deg[idx]; }
  sh[t] = s; __syncthreads();
  for (int off = 128; off > 0; off >>= 1){
    if (t < off) sh[t] += sh[t + off];
    __syncthreads();
  }
  if (t == 0) csum[chunk] = sh[0];
}

__global__ void k_scancsum(int* csum, int* rowStart){
  __shared__ int sh[128];
  int t = threadIdx.x;
  int v = (t < NCHUNK) ? csum[t] : 0;
  sh[t] = v; __syncthreads();
  for (int off = 1; off < 128; off <<= 1){
    int x = (t >= off) ? sh[t - off] : 0;
    __syncthreads();
    sh[t] += x;
    __syncthreads();
  }
  if (t < NCHUNK) csum[t] = sh[t] - v;  // exclusive
  if (t == 0) rowStart[NN] = EE;
}

__global__ void k_scanwithin(const int* __restrict__ deg, const int* __restrict__ csum,
                             int* __restrict__ rowStart){
  __shared__ int sh[256];
  int chunk = blockIdx.x, t = threadIdx.x;
  int base = chunk * 1024 + t * 4;
  int v[4];
  #pragma unroll
  for (int j = 0; j < 4; j++){ int idx = base + j; v[j] = (idx < NN) ? deg[idx] : 0; }
  int tot = v[0] + v[1] + v[2] + v[3];
  sh[t] = tot; __syncthreads();
  for (int off = 1; off < 256; off <<= 1){
    int x = (t >= off) ? sh[t - off] : 0;
    __syncthreads();
    sh[t] += x;
    __syncthreads();
  }
  int run = csum[chunk] + sh[t] - tot;
  #pragma unroll
  for (int j = 0; j < 4; j++){
    int idx = base + j;
    if (idx < NN){ rowStart[idx] = run; run += v[j]; }
  }
}

// ---------------- pass B: scatter with LDS cursor (no global atomics) ---------
__global__ __launch_bounds__(512) void k_scatter(const int* __restrict__ src,
    const int* __restrict__ dst, const int* __restrict__ rowStart,
    const int* __restrict__ bh, int* __restrict__ adj){
  __shared__ int cur[NPR];  // 100KB
  int b = blockIdx.x;
  int r = (b & 7) >> 1;
  int s = ((b >> 3) << 1) | (b & 1);
  int lo = r * NPR;
  for (int i = threadIdx.x; i < NPR; i += 512)
    cur[i] = rowStart[lo + i] + bh[(size_t)s * NN + lo + i];
  __syncthreads();
  int beg = s * ESL;
  for (int i = beg + threadIdx.x; i < beg + ESL; i += 512){
    int d = dst[i] - lo;
    if ((unsigned)d < NPR){
      int pos = atomicAdd(&cur[d], 1);
      adj[pos] = src[i];
    }
  }
}

__global__ void k_invdeg(const int* __restrict__ deg, float* __restrict__ invd){
  int i = blockIdx.x * blockDim.x + threadIdx.x;
  if (i < NN) invd[i] = 1.0f / fmaxf((float)deg[i], 1.0f);
}

// ---------------- casts ----------------
__global__ void k_castx(const float* __restrict__ x, uint32_t* __restrict__ B0){
  int i = blockIdx.x * 256 + threadIdx.x, stride = gridDim.x * 256;
  for (; i < NN * 64; i += stride){
    int row = i >> 6, c = (i & 63) << 1;
    B0[i] = pack2(x[row * 128 + c], x[row * 128 + c + 1]);
  }
}

// weights pre-arranged to LDS-friendly [k/4][col][4] bf16 layout
__global__ void k_castw(const float* __restrict__ Wl_g, const float* __restrict__ Wr_g,
                        const float* __restrict__ Wo_g, uint16_t* __restrict__ wbf,
                        uint16_t* __restrict__ wobf){
  int i = blockIdx.x * 256 + threadIdx.x, stride = gridDim.x * 256;
  for (; i < 172032; i += stride){
    if (i < 163840){
      int l = i >> 15, r = i & 32767;
      int kc = r >> 9, rem = r & 511, col = rem >> 2, k3 = rem & 3;
      int k = kc * 4 + k3;
      float v = (k < 128) ? Wl_g[l * 16384 + k * 128 + col]
                          : Wr_g[l * 16384 + (k - 128) * 128 + col];
      wbf[i] = bf16r(v);
    } else {
      int j = i - 163840;
      int kc = j >> 8, rem = j & 255, col = rem >> 2, k3 = rem & 3;
      int k = kc * 4 + k3;
      wobf[j] = bf16r(Wo_g[k * 64 + col]);
    }
  }
}

// ---------------- aggregation v4: full-row gather, uint4/lane, 4 edges/load --
// lane = (sub = lane>>4 edge slot, lc = lane&15 covering 256B row in 16B).
// chunk of 16 edges: 4 x uint4 loads + 4 adj loads per lane; pad slots clamp
// to adj[e-1] (L1-hot) and are corrected once after the reduction.
__global__ __launch_bounds__(256) void k_agg(const uint32_t* __restrict__ h,
    const int* __restrict__ rs, const int* __restrict__ adj,
    const float* __restrict__ invd, uint32_t* __restrict__ agg){
  int wv = (blockIdx.x * 256 + threadIdx.x) >> 6;
  int lane = threadIdx.x & 63;
  int nw = (gridDim.x * 256) >> 6;
  int sub = lane >> 4;   // 0..3: edge slot within group of 4
  int lc  = lane & 15;   // 16 x 16B covers the 256B row
  const uint32_t* hb = h + lc * 4;
  for (int node = wv; node < NN; node += nw){
    int s = rs[node], e = rs[node + 1];
    int len = e - s;
    float a0=0.f,a1=0.f,a2=0.f,a3=0.f,a4=0.f,a5=0.f,a6=0.f,a7=0.f;
    if (len > 0){
      int nch = (len + 15) >> 4;
      for (int c = 0; c < nch; c++){
        int base = s + c * 16 + sub;
        int rr[4];
        #pragma unroll
        for (int it = 0; it < 4; it++){
          int p = min(base + it * 4, e - 1);
          rr[it] = adj[p];
        }
        uint4 v[4];
        #pragma unroll
        for (int it = 0; it < 4; it++)
          v[it] = *(const uint4*)(hb + rr[it] * 64);
        #pragma unroll
        for (int it = 0; it < 4; it++){
          a0 += bflo(v[it].x); a1 += bfhi(v[it].x);
          a2 += bflo(v[it].y); a3 += bfhi(v[it].y);
          a4 += bflo(v[it].z); a5 += bfhi(v[it].z);
          a6 += bflo(v[it].w); a7 += bfhi(v[it].w);
        }
      }
      // reduce across the 4 sub-groups (lane strides 16, 32)
      a0 += __shfl_xor(a0,16); a1 += __shfl_xor(a1,16);
      a2 += __shfl_xor(a2,16); a3 += __shfl_xor(a3,16);
      a4 += __shfl_xor(a4,16); a5 += __shfl_xor(a5,16);
      a6 += __shfl_xor(a6,16); a7 += __shfl_xor(a7,16);
      a0 += __shfl_xor(a0,32); a1 += __shfl_xor(a1,32);
      a2 += __shfl_xor(a2,32); a3 += __shfl_xor(a3,32);
      a4 += __shfl_xor(a4,32); a5 += __shfl_xor(a5,32);
      a6 += __shfl_xor(a6,32); a7 += __shfl_xor(a7,32);
      int pad = nch * 16 - len;
      if (pad){
        int rl = adj[e - 1];
        uint4 vl = *(const uint4*)(hb + rl * 64);
        float fp = (float)pad;
        a0 -= fp * bflo(vl.x); a1 -= fp * bfhi(vl.x);
        a2 -= fp * bflo(vl.y); a3 -= fp * bfhi(vl.y);
        a4 -= fp * bflo(vl.z); a5 -= fp * bfhi(vl.z);
        a6 -= fp * bflo(vl.w); a7 -= fp * bfhi(vl.w);
      }
    }
    if (sub == 0){
      float id = invd[node];
      uint4 o;
      o.x = pack2(a0 * id, a1 * id);
      o.y = pack2(a2 * id, a3 * id);
      o.z = pack2(a4 * id, a5 * id);
      o.w = pack2(a6 * id, a7 * id);
      *(uint4*)(agg + node * 64 + lc * 4) = o;
    }
  }
}

// ---------------- fused GEMM: raw = [agg|h] @ [W_l;W_r] + b, + BN stats ------
// 512 threads = 8 waves x 32 rows (16 waves/CU at 64KB LDS).
__global__ __launch_bounds__(512) void k_gemm(const uint16_t* __restrict__ A0,
    const uint16_t* __restrict__ A1, const uint16_t* __restrict__ Wg,
    const float* __restrict__ bias, uint16_t* __restrict__ raw, float* __restrict__ stats){
  __shared__ uint16_t Wl[32768];  // 64KB: [k/4][128][4]
  int t = threadIdx.x;
  {
    const uint4* gw = (const uint4*)Wg;
    uint4* lw = (uint4*)Wl;
    #pragma unroll
    for (int i = 0; i < 8; i++) lw[t + i * 512] = gw[t + i * 512];
  }
  __syncthreads();
  int lane = t & 63, wid = t >> 6;     // 8 waves
  int rbase = blockIdx.x * 256 + wid * 32;
  int lm = lane & 15, lq = lane >> 4;
  const uint16_t* pa[2]; const uint16_t* ph[2];
  #pragma unroll
  for (int rf = 0; rf < 2; rf++){
    int grow = rbase + rf * 16 + lm;
    int crow = grow < NN ? grow : NN - 1;
    pa[rf] = A0 + (size_t)crow * 128;
    ph[rf] = A1 + (size_t)crow * 128;
  }
  int koffA = lq * 4;
  const uint16_t* wb = Wl + lq * 512 + lm * 4;
  f32x4 acc[2][8];
  #pragma unroll
  for (int rf = 0; rf < 2; rf++)
    #pragma unroll
    for (int c = 0; c < 8; c++){ acc[rf][c][0]=0.f; acc[rf][c][1]=0.f; acc[rf][c][2]=0.f; acc[rf][c][3]=0.f; }

  #pragma unroll
  for (int ch = 0; ch < 8; ++ch){
    const int kc = (ch & 3) * 32;
    S8 a[2];
    #pragma unroll
    for (int rf = 0; rf < 2; rf++){
      const uint16_t* p = (ch < 4 ? pa[rf] : ph[rf]) + kc + koffA;
      uint2 t0 = *(const uint2*)p;
      uint2 t1 = *(const uint2*)(p + 16);
      a[rf].u[0] = t0.x; a[rf].u[1] = t0.y; a[rf].u[2] = t1.x; a[rf].u[3] = t1.y;
    }
    const uint16_t* wc = wb + ch * 4096;
    #pragma unroll
    for (int cc = 0; cc < 8; cc++){
      S8 b;
      uint2 t0 = *(const uint2*)(wc + cc * 64);
      uint2 t1 = *(const uint2*)(wc + cc * 64 + 2048);
      b.u[0] = t0.x; b.u[1] = t0.y; b.u[2] = t1.x; b.u[3] = t1.y;
      #pragma unroll
      for (int rf = 0; rf < 2; rf++)
        acc[rf][cc] = __builtin_amdgcn_mfma_f32_16x16x32_bf16(a[rf].v, b.v, acc[rf][cc], 0, 0, 0);
    }
  }

  float bs[8];
  #pragma unroll
  for (int cc = 0; cc < 8; cc++) bs[cc] = bias[cc * 16 + lm];
  float sm[8] = {0,0,0,0,0,0,0,0}, sq[8] = {0,0,0,0,0,0,0,0};
  #pragma unroll
  for (int rf = 0; rf < 2; rf++){
    int rowb = rbase + rf * 16 + lq * 4;
    #pragma unroll
    for (int r = 0; r < 4; r++){
      int grow = rowb + r;
      if (grow < NN){
        uint16_t* orow = raw + (size_t)grow * 128 + lm;
        #pragma unroll
        for (int cc = 0; cc < 8; cc++){
          float v = acc[rf][cc][r] + bs[cc];
          orow[cc * 16] = bf16r(v);
          sm[cc] += v; sq[cc] += v * v;
        }
      }
    }
  }
  #pragma unroll
  for (int cc = 0; cc < 8; cc++){
    sm[cc] += __shfl_xor(sm[cc], 16); sm[cc] += __shfl_xor(sm[cc], 32);
    sq[cc] += __shfl_xor(sq[cc], 16); sq[cc] += __shfl_xor(sq[cc], 32);
  }
  if (lq == 0){
    #pragma unroll
    for (int cc = 0; cc < 8; cc++){
      atomicAdd(&stats[cc * 16 + lm], sm[cc]);
      atomicAdd(&stats[128 + cc * 16 + lm], sq[cc]);
    }
  }
}

// ---------------- BN+ReLU apply (computes coef per block from stats) ----------
__global__ __launch_bounds__(256) void k_bnrelu(const uint32_t* __restrict__ raw,
    uint32_t* __restrict__ hn, const float* __restrict__ stats,
    const float* __restrict__ gamma, const float* __restrict__ beta){
  __shared__ float cf[256];
  int t = threadIdx.x;
  if (t < 128){
    float mean = stats[t] * (1.0f / NN);
    float var = fmaxf(stats[128 + t] * (1.0f / NN) - mean * mean, 0.f);
    float a = gamma[t] * rsqrtf(var + BN_EPS);
    cf[t] = a;
    cf[128 + t] = beta[t] - mean * a;
  }
  __syncthreads();
  const uint2* rp = (const uint2*)raw;
  uint2* op = (uint2*)hn;
  int i = blockIdx.x * 256 + t, stride = gridDim.x * 256;
  for (; i < NN * 32; i += stride){
    uint2 v = rp[i];
    int c = (i & 31) * 4;
    float x0 = fmaxf(fmaf(bflo(v.x), cf[c],     cf[128 + c]),     0.f);
    float x1 = fmaxf(fmaf(bfhi(v.x), cf[c + 1], cf[129 + c]),     0.f);
    float x2 = fmaxf(fmaf(bflo(v.y), cf[c + 2], cf[130 + c]),     0.f);
    float x3 = fmaxf(fmaf(bfhi(v.y), cf[c + 3], cf[131 + c]),     0.f);
    uint2 o;
    o.x = pack2(x0, x1);
    o.y = pack2(x2, x3);
    op[i] = o;
  }
}

// ---------------- final projection: out = h @ W_o + b_o (f32 out) ------------
__global__ __launch_bounds__(512) void k_gemmout(const uint16_t* __restrict__ A1,
    const uint16_t* __restrict__ Wg, const float* __restrict__ bo, float* __restrict__ out){
  __shared__ uint16_t Wl[8192];  // 16KB: [k/4][64][4]
  int t = threadIdx.x;
  {
    const uint4* gw = (const uint4*)Wg;
    uint4* lw = (uint4*)Wl;
    #pragma unroll
    for (int i = 0; i < 2; i++) lw[t + i * 512] = gw[t + i * 512];
  }
  __syncthreads();
  int lane = t & 63, wid = t >> 6;
  int rbase = blockIdx.x * 256 + wid * 32;
  int lm = lane & 15, lq = lane >> 4;
  const uint16_t* ph[2];
  #pragma unroll
  for (int rf = 0; rf < 2; rf++){
    int grow = rbase + rf * 16 + lm;
    int crow = grow < NN ? grow : NN - 1;
    ph[rf] = A1 + (size_t)crow * 128;
  }
  const uint16_t* wbp = Wl + lq * 256 + lm * 4;
  f32x4 acc[2][4];
  #pragma unroll
  for (int rf = 0; rf < 2; rf++)
    #pragma unroll
    for (int c = 0; c < 4; c++){ acc[rf][c][0]=0.f; acc[rf][c][1]=0.f; acc[rf][c][2]=0.f; acc[rf][c][3]=0.f; }
  #pragma unroll
  for (int ch = 0; ch < 4; ++ch){
    int kc = ch * 32;
    S8 a[2];
    #pragma unroll
    for (int rf = 0; rf < 2; rf++){
      const uint16_t* p = ph[rf] + kc + lq * 4;
      uint2 t0 = *(const uint2*)p;
      uint2 t1 = *(const uint2*)(p + 16);
      a[rf].u[0] = t0.x; a[rf].u[1] = t0.y; a[rf].u[2] = t1.x; a[rf].u[3] = t1.y;
    }
    const uint16_t* wc = wbp + ch * 2048;
    #pragma unroll
    for (int cc = 0; cc < 4; cc++){
      S8 b;
      uint2 t0 = *(const uint2*)(wc + cc * 64);
      uint2 t1 = *(const uint2*)(wc + cc * 64 + 1024);
      b.u[0] = t0.x; b.u[1] = t0.y; b.u[2] = t1.x; b.u[3] = t1.y;
      #pragma unroll
      for (int rf = 0; rf < 2; rf++)
        acc[rf][cc] = __builtin_amdgcn_mfma_f32_16x16x32_bf16(a[rf].v, b.v, acc[rf][cc], 0, 0, 0);
    }
  }
  float bs[4];
  #pragma unroll
  for (int cc = 0; cc < 4; cc++) bs[cc] = bo[cc * 16 + lm];
  #pragma unroll
  for (int rf = 0; rf < 2; rf++){
    int rowb = rbase + rf * 16 + lq * 4;
    #pragma unroll
    for (int r = 0; r < 4; r++){
      int grow = rowb + r;
      if (grow < NN){
        float* orow = out + (size_t)grow * 64 + lm;
        #pragma unroll
        for (int cc = 0; cc < 4; cc++) orow[cc * 16] = acc[rf][cc][r] + bs[cc];
      }
    }
  }
}

extern "C" void kernel_launch(void* const* d_in, const int* in_sizes, int n_in,
                              void* d_out, int out_size, void* d_ws, size_t ws_size,
                              hipStream_t stream){
  const float* x      = (const float*)d_in[0];
  const void*  edges  = d_in[1];
  const float* Wl_g   = (const float*)d_in[2];
  const float* bl_g   = (const float*)d_in[3];
  const float* Wr_g   = (const float*)d_in[4];
  const float* gm_g   = (const float*)d_in[5];
  const float* bt_g   = (const float*)d_in[6];
  const float* Wo_g   = (const float*)d_in[7];
  const float* bo_g   = (const float*)d_in[8];
  float* out = (float*)d_out;

  char* ws = (char*)d_ws;
  size_t off = 0;
  auto alloc = [&](size_t bytes) -> char* {
    char* p = ws + off;
    off = (off + bytes + 255) & ~(size_t)255;
    return p;
  };
  int*      flag     = (int*)alloc(4);
  int*      deg      = (int*)alloc(4 * NN);
  int*      rowStart = (int*)alloc(4 * (NN + 1));
  float*    invd     = (float*)alloc(4 * NN);
  int*      csum     = (int*)alloc(4 * 128);
  int*      adj      = (int*)alloc(4 * (EE + 8));
  uint16_t* wbf      = (uint16_t*)alloc(2 * 5 * 32768);
  uint16_t* wobf     = (uint16_t*)alloc(2 * 8192);
  float*    stats    = (float*)alloc(4 * 256 * NLAYERS);  // per-layer segments
  const size_t NPAD = 100096;  // 391 * 256
  uint16_t* B0 = (uint16_t*)alloc(2 * NPAD * 128);  // h_norm (state)
  uint16_t* B1 = (uint16_t*)alloc(2 * NPAD * 128);  // raw
  uint16_t* B2 = (uint16_t*)alloc(2 * NPAD * 128);  // agg
  // aliases: both dead before the layer loop's first writes to B1/B2
  int* e32 = (int*)B2;   // 12.8MB  (consumed by k_scatter)
  int* bh  = (int*)B1;   // 25.6MB  (SS*NN*4 = 25.6e6 <= 25.62e6)

  hipMemsetAsync(stats, 0, 4 * 256 * NLAYERS, stream);

  k_detect<<<1, 64, 0, stream>>>((const long long*)edges, flag);
  k_conv<<<2048, 256, 0, stream>>>(edges, flag, e32);
  k_hist<<<RR * SS, 512, 0, stream>>>(e32 + EE, bh);
  k_scanhist<<<391, 256, 0, stream>>>(bh, deg);
  k_chunksum<<<NCHUNK, 256, 0, stream>>>(deg, csum);
  k_scancsum<<<1, 128, 0, stream>>>(csum, rowStart);
  k_scanwithin<<<NCHUNK, 256, 0, stream>>>(deg, csum, rowStart);
  k_invdeg<<<391, 256, 0, stream>>>(deg, invd);
  k_scatter<<<RR * SS, 512, 0, stream>>>(e32, e32 + EE, rowStart, bh, adj);
  k_castx<<<2048, 256, 0, stream>>>(x, (uint32_t*)B0);
  k_castw<<<256, 256, 0, stream>>>(Wl_g, Wr_g, Wo_g, wbf, wobf);

  for (int l = 0; l < NLAYERS; l++){
    float* st = stats + (size_t)l * 256;
    k_agg<<<2048, 256, 0, stream>>>((const uint32_t*)B0, rowStart, adj, invd, (uint32_t*)B2);
    k_gemm<<<391, 512, 0, stream>>>(B2, B0, wbf + (size_t)l * 32768, bl_g + l * 128, B1, st);
    k_bnrelu<<<2048, 256, 0, stream>>>((const uint32_t*)B1, (uint32_t*)B0, st,
                                       gm_g + l * 128, bt_g + l * 128);
  }
  k_gemmout<<<391, 512, 0, stream>>>(B0, wobf, bo_g, out);
}

// Round 9
// 712.700 us; speedup vs baseline: 3.6717x; 1.4094x over previous
//
#include <hip/hip_runtime.h>
#include <stdint.h>

#define NN 100000
#define EE 1600000
#define NLAYERS 5
#define BN_EPS 1e-5f
#define NCHUNK 98    // ceil(NN/1024)
#define RR 4         // node ranges (25K nodes each -> 100KB LDS hist)
#define SS 64        // edge slices
#define NPR 25000    // nodes per range
#define ESL 25000    // edges per slice

typedef __attribute__((ext_vector_type(8))) short short8;
typedef __attribute__((ext_vector_type(4))) float f32x4;

union S8 { short8 v; uint32_t u[4]; };

__device__ inline uint16_t bf16r(float a){
  uint32_t u = __float_as_uint(a);
  u = (u + 0x7fffu + ((u >> 16) & 1u)) >> 16;
  return (uint16_t)u;
}
__device__ inline uint32_t pack2(float a, float b){
  return (uint32_t)bf16r(a) | ((uint32_t)bf16r(b) << 16);
}
__device__ inline float bflo(uint32_t v){ return __uint_as_float(v << 16); }
__device__ inline float bfhi(uint32_t v){ return __uint_as_float(v & 0xffff0000u); }

// ---------------- edge dtype detection (int64 vs int32, JAX x64 ambiguity) ----
__global__ void k_detect(const long long* e, int* flag){
  if (threadIdx.x == 0){
    int f = 1;
    for (int i = 0; i < 8; i++){ long long v = e[i]; if (v < 0 || v >= NN) f = 0; }
    *flag = f;  // 1 => int64 data, 0 => int32 data
  }
}

// ---------------- edge convert to int32 (src at [0,E), dst at [E,2E)) ---------
__global__ __launch_bounds__(256) void k_conv(const void* ep, const int* __restrict__ flag,
                                              int* __restrict__ e32o){
  int f = *flag;
  int i = blockIdx.x * 256 + threadIdx.x, stride = gridDim.x * 256;
  const long long* e64 = (const long long*)ep;
  const int* ei = (const int*)ep;
  for (; i < 2 * EE; i += stride) e32o[i] = f ? (int)e64[i] : ei[i];
}

// ---------------- pass A: per-(slice,range) LDS histogram, no global atomics --
__global__ __launch_bounds__(512) void k_hist(const int* __restrict__ dst, int* __restrict__ bh){
  __shared__ int hist[NPR];  // 100KB
  int b = blockIdx.x;
  int r = (b & 7) >> 1;
  int s = ((b >> 3) << 1) | (b & 1);
  int lo = r * NPR;
  for (int i = threadIdx.x; i < NPR; i += 512) hist[i] = 0;
  __syncthreads();
  int beg = s * ESL;
  for (int i = beg + threadIdx.x; i < beg + ESL; i += 512){
    int d = dst[i] - lo;
    if ((unsigned)d < NPR) atomicAdd(&hist[d], 1);
  }
  __syncthreads();
  for (int i = threadIdx.x; i < NPR; i += 512)
    bh[(size_t)s * NN + lo + i] = hist[i];
}

// ---------------- cross-slice exclusive scan per node; total -> deg -----------
__global__ __launch_bounds__(256) void k_scanhist(int* __restrict__ bh, int* __restrict__ deg){
  int n = blockIdx.x * 256 + threadIdx.x;
  if (n < NN){
    int run = 0;
    #pragma unroll 4
    for (int s = 0; s < SS; s++){
      size_t p = (size_t)s * NN + n;
      int v = bh[p]; bh[p] = run; run += v;
    }
    deg[n] = run;
  }
}

// ---------------- global node scan (3 kernels) ----------------
__global__ void k_chunksum(const int* __restrict__ deg, int* __restrict__ csum){
  __shared__ int sh[256];
  int chunk = blockIdx.x, t = threadIdx.x;
  int base = chunk * 1024 + t * 4;
  int s = 0;
  #pragma unroll
  for (int j = 0; j < 4; j++){ int idx = base + j; if (idx < NN) s += deg[idx]; }
  sh[t] = s; __syncthreads();
  for (int off = 128; off > 0; off >>= 1){
    if (t < off) sh[t] += sh[t + off];
    __syncthreads();
  }
  if (t == 0) csum[chunk] = sh[0];
}

__global__ void k_scancsum(int* csum, int* rowStart){
  __shared__ int sh[128];
  int t = threadIdx.x;
  int v = (t < NCHUNK) ? csum[t] : 0;
  sh[t] = v; __syncthreads();
  for (int off = 1; off < 128; off <<= 1){
    int x = (t >= off) ? sh[t - off] : 0;
    __syncthreads();
    sh[t] += x;
    __syncthreads();
  }
  if (t < NCHUNK) csum[t] = sh[t] - v;  // exclusive
  if (t == 0) rowStart[NN] = EE;
}

__global__ void k_scanwithin(const int* __restrict__ deg, const int* __restrict__ csum,
                             int* __restrict__ rowStart){
  __shared__ int sh[256];
  int chunk = blockIdx.x, t = threadIdx.x;
  int base = chunk * 1024 + t * 4;
  int v[4];
  #pragma unroll
  for (int j = 0; j < 4; j++){ int idx = base + j; v[j] = (idx < NN) ? deg[idx] : 0; }
  int tot = v[0] + v[1] + v[2] + v[3];
  sh[t] = tot; __syncthreads();
  for (int off = 1; off < 256; off <<= 1){
    int x = (t >= off) ? sh[t - off] : 0;
    __syncthreads();
    sh[t] += x;
    __syncthreads();
  }
  int run = csum[chunk] + sh[t] - tot;
  #pragma unroll
  for (int j = 0; j < 4; j++){
    int idx = base + j;
    if (idx < NN){ rowStart[idx] = run; run += v[j]; }
  }
}

// ---------------- pass B: scatter with LDS cursor (no global atomics) ---------
__global__ __launch_bounds__(512) void k_scatter(const int* __restrict__ src,
    const int* __restrict__ dst, const int* __restrict__ rowStart,
    const int* __restrict__ bh, int* __restrict__ adj){
  __shared__ int cur[NPR];  // 100KB
  int b = blockIdx.x;
  int r = (b & 7) >> 1;
  int s = ((b >> 3) << 1) | (b & 1);
  int lo = r * NPR;
  for (int i = threadIdx.x; i < NPR; i += 512)
    cur[i] = rowStart[lo + i] + bh[(size_t)s * NN + lo + i];
  __syncthreads();
  int beg = s * ESL;
  for (int i = beg + threadIdx.x; i < beg + ESL; i += 512){
    int d = dst[i] - lo;
    if ((unsigned)d < NPR){
      int pos = atomicAdd(&cur[d], 1);
      adj[pos] = src[i];
    }
  }
}

__global__ void k_invdeg(const int* __restrict__ deg, float* __restrict__ invd){
  int i = blockIdx.x * blockDim.x + threadIdx.x;
  if (i < NN) invd[i] = 1.0f / fmaxf((float)deg[i], 1.0f);
}

// ---------------- casts ----------------
__global__ void k_castx(const float* __restrict__ x, uint32_t* __restrict__ B0){
  int i = blockIdx.x * 256 + threadIdx.x, stride = gridDim.x * 256;
  for (; i < NN * 64; i += stride){
    int row = i >> 6, c = (i & 63) << 1;
    B0[i] = pack2(x[row * 128 + c], x[row * 128 + c + 1]);
  }
}

// weights pre-arranged to LDS-friendly [k/4][col][4] bf16 layout
__global__ void k_castw(const float* __restrict__ Wl_g, const float* __restrict__ Wr_g,
                        const float* __restrict__ Wo_g, uint16_t* __restrict__ wbf,
                        uint16_t* __restrict__ wobf){
  int i = blockIdx.x * 256 + threadIdx.x, stride = gridDim.x * 256;
  for (; i < 172032; i += stride){
    if (i < 163840){
      int l = i >> 15, r = i & 32767;
      int kc = r >> 9, rem = r & 511, col = rem >> 2, k3 = rem & 3;
      int k = kc * 4 + k3;
      float v = (k < 128) ? Wl_g[l * 16384 + k * 128 + col]
                          : Wr_g[l * 16384 + (k - 128) * 128 + col];
      wbf[i] = bf16r(v);
    } else {
      int j = i - 163840;
      int kc = j >> 8, rem = j & 255, col = rem >> 2, k3 = rem & 3;
      int k = kc * 4 + k3;
      wobf[j] = bf16r(Wo_g[k * 64 + col]);
    }
  }
}

// ---------------- aggregation v4: full-row gather, uint4/lane, 4 edges/load --
__global__ __launch_bounds__(256) void k_agg(const uint32_t* __restrict__ h,
    const int* __restrict__ rs, const int* __restrict__ adj,
    const float* __restrict__ invd, uint32_t* __restrict__ agg){
  int wv = (blockIdx.x * 256 + threadIdx.x) >> 6;
  int lane = threadIdx.x & 63;
  int nw = (gridDim.x * 256) >> 6;
  int sub = lane >> 4;   // 0..3: edge slot within group of 4
  int lc  = lane & 15;   // 16 x 16B covers the 256B row
  const uint32_t* hb = h + lc * 4;
  for (int node = wv; node < NN; node += nw){
    int s = rs[node], e = rs[node + 1];
    int len = e - s;
    float a0=0.f,a1=0.f,a2=0.f,a3=0.f,a4=0.f,a5=0.f,a6=0.f,a7=0.f;
    if (len > 0){
      int nch = (len + 15) >> 4;
      for (int c = 0; c < nch; c++){
        int base = s + c * 16 + sub;
        int rr[4];
        #pragma unroll
        for (int it = 0; it < 4; it++){
          int p = min(base + it * 4, e - 1);
          rr[it] = adj[p];
        }
        uint4 v[4];
        #pragma unroll
        for (int it = 0; it < 4; it++)
          v[it] = *(const uint4*)(hb + rr[it] * 64);
        #pragma unroll
        for (int it = 0; it < 4; it++){
          a0 += bflo(v[it].x); a1 += bfhi(v[it].x);
          a2 += bflo(v[it].y); a3 += bfhi(v[it].y);
          a4 += bflo(v[it].z); a5 += bfhi(v[it].z);
          a6 += bflo(v[it].w); a7 += bfhi(v[it].w);
        }
      }
      a0 += __shfl_xor(a0,16); a1 += __shfl_xor(a1,16);
      a2 += __shfl_xor(a2,16); a3 += __shfl_xor(a3,16);
      a4 += __shfl_xor(a4,16); a5 += __shfl_xor(a5,16);
      a6 += __shfl_xor(a6,16); a7 += __shfl_xor(a7,16);
      a0 += __shfl_xor(a0,32); a1 += __shfl_xor(a1,32);
      a2 += __shfl_xor(a2,32); a3 += __shfl_xor(a3,32);
      a4 += __shfl_xor(a4,32); a5 += __shfl_xor(a5,32);
      a6 += __shfl_xor(a6,32); a7 += __shfl_xor(a7,32);
      int pad = nch * 16 - len;
      if (pad){
        int rl = adj[e - 1];
        uint4 vl = *(const uint4*)(hb + rl * 64);
        float fp = (float)pad;
        a0 -= fp * bflo(vl.x); a1 -= fp * bfhi(vl.x);
        a2 -= fp * bflo(vl.y); a3 -= fp * bfhi(vl.y);
        a4 -= fp * bflo(vl.z); a5 -= fp * bfhi(vl.z);
        a6 -= fp * bflo(vl.w); a7 -= fp * bfhi(vl.w);
      }
    }
    if (sub == 0){
      float id = invd[node];
      uint4 o;
      o.x = pack2(a0 * id, a1 * id);
      o.y = pack2(a2 * id, a3 * id);
      o.z = pack2(a4 * id, a5 * id);
      o.w = pack2(a6 * id, a7 * id);
      *(uint4*)(agg + node * 64 + lc * 4) = o;
    }
  }
}

// ---------------- fused GEMM: raw = [agg|h] @ [W_l;W_r] + b, + BN stats ------
// 512 threads = 8 waves x 32 rows. Stats: wave -> LDS (atomic, cheap) ->
// ONE global atomicAdd set per block (256 instead of 2048 per block).
__global__ __launch_bounds__(512) void k_gemm(const uint16_t* __restrict__ A0,
    const uint16_t* __restrict__ A1, const uint16_t* __restrict__ Wg,
    const float* __restrict__ bias, uint16_t* __restrict__ raw, float* __restrict__ stats){
  __shared__ uint16_t Wl[32768];  // 64KB: [k/4][128][4]
  __shared__ float sred[256];     // block-level BN stats accumulator
  int t = threadIdx.x;
  {
    const uint4* gw = (const uint4*)Wg;
    uint4* lw = (uint4*)Wl;
    #pragma unroll
    for (int i = 0; i < 8; i++) lw[t + i * 512] = gw[t + i * 512];
  }
  if (t < 256) sred[t] = 0.f;
  __syncthreads();
  int lane = t & 63, wid = t >> 6;     // 8 waves
  int rbase = blockIdx.x * 256 + wid * 32;
  int lm = lane & 15, lq = lane >> 4;
  const uint16_t* pa[2]; const uint16_t* ph[2];
  #pragma unroll
  for (int rf = 0; rf < 2; rf++){
    int grow = rbase + rf * 16 + lm;
    int crow = grow < NN ? grow : NN - 1;
    pa[rf] = A0 + (size_t)crow * 128;
    ph[rf] = A1 + (size_t)crow * 128;
  }
  int koffA = lq * 4;
  const uint16_t* wb = Wl + lq * 512 + lm * 4;
  f32x4 acc[2][8];
  #pragma unroll
  for (int rf = 0; rf < 2; rf++)
    #pragma unroll
    for (int c = 0; c < 8; c++){ acc[rf][c][0]=0.f; acc[rf][c][1]=0.f; acc[rf][c][2]=0.f; acc[rf][c][3]=0.f; }

  #pragma unroll
  for (int ch = 0; ch < 8; ++ch){
    const int kc = (ch & 3) * 32;
    S8 a[2];
    #pragma unroll
    for (int rf = 0; rf < 2; rf++){
      const uint16_t* p = (ch < 4 ? pa[rf] : ph[rf]) + kc + koffA;
      uint2 t0 = *(const uint2*)p;
      uint2 t1 = *(const uint2*)(p + 16);
      a[rf].u[0] = t0.x; a[rf].u[1] = t0.y; a[rf].u[2] = t1.x; a[rf].u[3] = t1.y;
    }
    const uint16_t* wc = wb + ch * 4096;
    #pragma unroll
    for (int cc = 0; cc < 8; cc++){
      S8 b;
      uint2 t0 = *(const uint2*)(wc + cc * 64);
      uint2 t1 = *(const uint2*)(wc + cc * 64 + 2048);
      b.u[0] = t0.x; b.u[1] = t0.y; b.u[2] = t1.x; b.u[3] = t1.y;
      #pragma unroll
      for (int rf = 0; rf < 2; rf++)
        acc[rf][cc] = __builtin_amdgcn_mfma_f32_16x16x32_bf16(a[rf].v, b.v, acc[rf][cc], 0, 0, 0);
    }
  }

  float bs[8];
  #pragma unroll
  for (int cc = 0; cc < 8; cc++) bs[cc] = bias[cc * 16 + lm];
  float sm[8] = {0,0,0,0,0,0,0,0}, sq[8] = {0,0,0,0,0,0,0,0};
  #pragma unroll
  for (int rf = 0; rf < 2; rf++){
    int rowb = rbase + rf * 16 + lq * 4;
    #pragma unroll
    for (int r = 0; r < 4; r++){
      int grow = rowb + r;
      if (grow < NN){
        uint16_t* orow = raw + (size_t)grow * 128 + lm;
        #pragma unroll
        for (int cc = 0; cc < 8; cc++){
          float v = acc[rf][cc][r] + bs[cc];
          orow[cc * 16] = bf16r(v);
          sm[cc] += v; sq[cc] += v * v;
        }
      }
    }
  }
  #pragma unroll
  for (int cc = 0; cc < 8; cc++){
    sm[cc] += __shfl_xor(sm[cc], 16); sm[cc] += __shfl_xor(sm[cc], 32);
    sq[cc] += __shfl_xor(sq[cc], 16); sq[cc] += __shfl_xor(sq[cc], 32);
  }
  if (lq == 0){
    #pragma unroll
    for (int cc = 0; cc < 8; cc++){
      atomicAdd(&sred[cc * 16 + lm], sm[cc]);
      atomicAdd(&sred[128 + cc * 16 + lm], sq[cc]);
    }
  }
  __syncthreads();
  if (t < 256) atomicAdd(&stats[t], sred[t]);
}

// ---------------- BN+ReLU apply (computes coef per block from stats) ----------
__global__ __launch_bounds__(256) void k_bnrelu(const uint32_t* __restrict__ raw,
    uint32_t* __restrict__ hn, const float* __restrict__ stats,
    const float* __restrict__ gamma, const float* __restrict__ beta){
  __shared__ float cf[256];
  int t = threadIdx.x;
  if (t < 128){
    float mean = stats[t] * (1.0f / NN);
    float var = fmaxf(stats[128 + t] * (1.0f / NN) - mean * mean, 0.f);
    float a = gamma[t] * rsqrtf(var + BN_EPS);
    cf[t] = a;
    cf[128 + t] = beta[t] - mean * a;
  }
  __syncthreads();
  const uint2* rp = (const uint2*)raw;
  uint2* op = (uint2*)hn;
  int i = blockIdx.x * 256 + t, stride = gridDim.x * 256;
  for (; i < NN * 32; i += stride){
    uint2 v = rp[i];
    int c = (i & 31) * 4;
    float x0 = fmaxf(fmaf(bflo(v.x), cf[c],     cf[128 + c]),     0.f);
    float x1 = fmaxf(fmaf(bfhi(v.x), cf[c + 1], cf[129 + c]),     0.f);
    float x2 = fmaxf(fmaf(bflo(v.y), cf[c + 2], cf[130 + c]),     0.f);
    float x3 = fmaxf(fmaf(bfhi(v.y), cf[c + 3], cf[131 + c]),     0.f);
    uint2 o;
    o.x = pack2(x0, x1);
    o.y = pack2(x2, x3);
    op[i] = o;
  }
}

// ---------------- final projection: out = h @ W_o + b_o (f32 out) ------------
__global__ __launch_bounds__(512) void k_gemmout(const uint16_t* __restrict__ A1,
    const uint16_t* __restrict__ Wg, const float* __restrict__ bo, float* __restrict__ out){
  __shared__ uint16_t Wl[8192];  // 16KB: [k/4][64][4]
  int t = threadIdx.x;
  {
    const uint4* gw = (const uint4*)Wg;
    uint4* lw = (uint4*)Wl;
    #pragma unroll
    for (int i = 0; i < 2; i++) lw[t + i * 512] = gw[t + i * 512];
  }
  __syncthreads();
  int lane = t & 63, wid = t >> 6;
  int rbase = blockIdx.x * 256 + wid * 32;
  int lm = lane & 15, lq = lane >> 4;
  const uint16_t* ph[2];
  #pragma unroll
  for (int rf = 0; rf < 2; rf++){
    int grow = rbase + rf * 16 + lm;
    int crow = grow < NN ? grow : NN - 1;
    ph[rf] = A1 + (size_t)crow * 128;
  }
  const uint16_t* wbp = Wl + lq * 256 + lm * 4;
  f32x4 acc[2][4];
  #pragma unroll
  for (int rf = 0; rf < 2; rf++)
    #pragma unroll
    for (int c = 0; c < 4; c++){ acc[rf][c][0]=0.f; acc[rf][c][1]=0.f; acc[rf][c][2]=0.f; acc[rf][c][3]=0.f; }
  #pragma unroll
  for (int ch = 0; ch < 4; ++ch){
    int kc = ch * 32;
    S8 a[2];
    #pragma unroll
    for (int rf = 0; rf < 2; rf++){
      const uint16_t* p = ph[rf] + kc + lq * 4;
      uint2 t0 = *(const uint2*)p;
      uint2 t1 = *(const uint2*)(p + 16);
      a[rf].u[0] = t0.x; a[rf].u[1] = t0.y; a[rf].u[2] = t1.x; a[rf].u[3] = t1.y;
    }
    const uint16_t* wc = wbp + ch * 2048;
    #pragma unroll
    for (int cc = 0; cc < 4; cc++){
      S8 b;
      uint2 t0 = *(const uint2*)(wc + cc * 64);
      uint2 t1 = *(const uint2*)(wc + cc * 64 + 1024);
      b.u[0] = t0.x; b.u[1] = t0.y; b.u[2] = t1.x; b.u[3] = t1.y;
      #pragma unroll
      for (int rf = 0; rf < 2; rf++)
        acc[rf][cc] = __builtin_amdgcn_mfma_f32_16x16x32_bf16(a[rf].v, b.v, acc[rf][cc], 0, 0, 0);
    }
  }
  float bs[4];
  #pragma unroll
  for (int cc = 0; cc < 4; cc++) bs[cc] = bo[cc * 16 + lm];
  #pragma unroll
  for (int rf = 0; rf < 2; rf++){
    int rowb = rbase + rf * 16 + lq * 4;
    #pragma unroll
    for (int r = 0; r < 4; r++){
      int grow = rowb + r;
      if (grow < NN){
        float* orow = out + (size_t)grow * 64 + lm;
        #pragma unroll
        for (int cc = 0; cc < 4; cc++) orow[cc * 16] = acc[rf][cc][r] + bs[cc];
      }
    }
  }
}

extern "C" void kernel_launch(void* const* d_in, const int* in_sizes, int n_in,
                              void* d_out, int out_size, void* d_ws, size_t ws_size,
                              hipStream_t stream){
  const float* x      = (const float*)d_in[0];
  const void*  edges  = d_in[1];
  const float* Wl_g   = (const float*)d_in[2];
  const float* bl_g   = (const float*)d_in[3];
  const float* Wr_g   = (const float*)d_in[4];
  const float* gm_g   = (const float*)d_in[5];
  const float* bt_g   = (const float*)d_in[6];
  const float* Wo_g   = (const float*)d_in[7];
  const float* bo_g   = (const float*)d_in[8];
  float* out = (float*)d_out;

  char* ws = (char*)d_ws;
  size_t off = 0;
  auto alloc = [&](size_t bytes) -> char* {
    char* p = ws + off;
    off = (off + bytes + 255) & ~(size_t)255;
    return p;
  };
  int*      flag     = (int*)alloc(4);
  int*      deg      = (int*)alloc(4 * NN);
  int*      rowStart = (int*)alloc(4 * (NN + 1));
  float*    invd     = (float*)alloc(4 * NN);
  int*      csum     = (int*)alloc(4 * 128);
  int*      adj      = (int*)alloc(4 * (EE + 8));
  uint16_t* wbf      = (uint16_t*)alloc(2 * 5 * 32768);
  uint16_t* wobf     = (uint16_t*)alloc(2 * 8192);
  float*    stats    = (float*)alloc(4 * 256 * NLAYERS);  // per-layer segments
  const size_t NPAD = 100096;  // 391 * 256
  uint16_t* B0 = (uint16_t*)alloc(2 * NPAD * 128);  // h_norm (state)
  uint16_t* B1 = (uint16_t*)alloc(2 * NPAD * 128);  // raw
  uint16_t* B2 = (uint16_t*)alloc(2 * NPAD * 128);  // agg
  // aliases: both dead before the layer loop's first writes to B1/B2
  int* e32 = (int*)B2;   // 12.8MB  (consumed by k_scatter)
  int* bh  = (int*)B1;   // 25.6MB  (SS*NN*4 = 25.6e6 <= 25.62e6)

  hipMemsetAsync(stats, 0, 4 * 256 * NLAYERS, stream);

  k_detect<<<1, 64, 0, stream>>>((const long long*)edges, flag);
  k_conv<<<2048, 256, 0, stream>>>(edges, flag, e32);
  k_hist<<<RR * SS, 512, 0, stream>>>(e32 + EE, bh);
  k_scanhist<<<391, 256, 0, stream>>>(bh, deg);
  k_chunksum<<<NCHUNK, 256, 0, stream>>>(deg, csum);
  k_scancsum<<<1, 128, 0, stream>>>(csum, rowStart);
  k_scanwithin<<<NCHUNK, 256, 0, stream>>>(deg, csum, rowStart);
  k_invdeg<<<391, 256, 0, stream>>>(deg, invd);
  k_scatter<<<RR * SS, 512, 0, stream>>>(e32, e32 + EE, rowStart, bh, adj);
  k_castx<<<2048, 256, 0, stream>>>(x, (uint32_t*)B0);
  k_castw<<<256, 256, 0, stream>>>(Wl_g, Wr_g, Wo_g, wbf, wobf);

  for (int l = 0; l < NLAYERS; l++){
    float* st = stats + (size_t)l * 256;
    k_agg<<<2048, 256, 0, stream>>>((const uint32_t*)B0, rowStart, adj, invd, (uint32_t*)B2);
    k_gemm<<<391, 512, 0, stream>>>(B2, B0, wbf + (size_t)l * 32768, bl_g + l * 128, B1, st);
    k_bnrelu<<<2048, 256, 0, stream>>>((const uint32_t*)B1, (uint32_t*)B0, st,
                                       gm_g + l * 128, bt_g + l * 128);
  }
  k_gemmout<<<391, 512, 0, stream>>>(B0, wobf, bo_g, out);
}